// Round 7
// baseline (250.656 us; speedup 1.0000x reference)
//
#include <hip/hip_runtime.h>
#include <hip/hip_bf16.h>
#include <hip/hip_fp16.h>

#define BATCH 8
#define NSEQ 1024
#define DIMM 448
#define NHEAD 7
#define HDIM 64
#define MROWS (BATCH*NSEQ)   // 8192
#define KDIM 448
#define SCALE_F 0.125f
#define NROW (56*NSEQ)       // 57344 q-rows

typedef short short8 __attribute__((ext_vector_type(8)));
typedef int   int4v  __attribute__((ext_vector_type(4)));
typedef float floatx16 __attribute__((ext_vector_type(16)));
typedef unsigned int u32;

#define MFMA32(a,b,c) __builtin_amdgcn_mfma_f32_32x32x16_bf16(a,b,c,0,0,0)

__device__ __forceinline__ unsigned short f2bf(float f){
    __hip_bfloat16 h = __float2bfloat16(f);
    return *reinterpret_cast<unsigned short*>(&h);
}
__device__ __forceinline__ float bf2f(unsigned short u){
    __hip_bfloat16 h; *reinterpret_cast<unsigned short*>(&h) = u;
    return __bfloat162float(h);
}
__device__ __forceinline__ float h2f(unsigned short u){
    __half h; *reinterpret_cast<unsigned short*>(&h) = u;
    return __half2float(h);
}
__device__ __forceinline__ unsigned short f2h(float f){
    __half h = __float2half(f);
    return *reinterpret_cast<unsigned short*>(&h);
}
__device__ __forceinline__ short8 i4_to_s8(int4v v){
    union { int4v i; short8 s; } u; u.i = v; return u.s;
}

// ---------------------------------------------------------------------------
// prep_all: fused conversions.
//   [0,3584)     x -> xh bf16
//   [3584,4032)  ek -> ekh bf16
//   [4032,4228)  wqv -> wqvTh [896][448] bf16 (transposed)
//   [4228,4326)  wout -> woTh/woTl [448][448] split bf16 (transposed)
//   [4326,6118)  eb -> bp fp16 prescaled, attn granule order (2 units/block)
// bp: slab per (h, qt32, mt32) = 64 lanes x 16 fp16; lane (lq,lh) holds
//     q = qt*32+lq, m = mt*32 + j + 8g + 4lh  at offset lane*16 + g*4 + j
// ---------------------------------------------------------------------------
__global__ __launch_bounds__(256)
void prep_all(const float* __restrict__ x, const float* __restrict__ ek,
              const float* __restrict__ wqv, const float* __restrict__ wout,
              const float* __restrict__ eb,
              unsigned short* __restrict__ xh, unsigned short* __restrict__ ekh,
              unsigned short* __restrict__ wqvTh, unsigned short* __restrict__ woTh,
              unsigned short* __restrict__ woTl, unsigned short* __restrict__ bp)
{
    __shared__ float T2[2][32][65];
    const int bx = blockIdx.x, tid = threadIdx.x;

    if (bx < 3584) {
        int i = bx*256 + tid;
        float4 v = ((const float4*)x)[i];
        ((ushort4*)xh)[i] = make_ushort4(f2bf(v.x), f2bf(v.y), f2bf(v.z), f2bf(v.w));
    } else if (bx < 4032) {
        int i = (bx-3584)*256 + tid;
        float4 v = ((const float4*)ek)[i];
        ((ushort4*)ekh)[i] = make_ushort4(f2bf(v.x), f2bf(v.y), f2bf(v.z), f2bf(v.w));
    } else if (bx < 4228) {
        int lid = (bx-4032)*4 + (tid>>6);    // 0..783 = kc(56) x ng(14)
        int kc = lid % 56, ng = lid / 56;
        int n = ng*64 + (tid&63);
        unsigned short h[8];
#pragma unroll
        for (int j = 0; j < 8; ++j) h[j] = f2bf(wqv[(size_t)(kc*8+j)*896 + n]);
        size_t o = (size_t)n*KDIM + kc*8;
        *(ushort4*)(wqvTh + o)     = make_ushort4(h[0],h[1],h[2],h[3]);
        *(ushort4*)(wqvTh + o + 4) = make_ushort4(h[4],h[5],h[6],h[7]);
    } else if (bx < 4326) {
        int lid = (bx-4228)*4 + (tid>>6);    // 0..391 = kc(56) x ng(7)
        int kc = lid % 56, ng = lid / 56;
        int n = ng*64 + (tid&63);
        unsigned short h[8], l[8];
#pragma unroll
        for (int j = 0; j < 8; ++j) {
            float f = wout[(size_t)(kc*8+j)*DIMM + n];
            h[j] = f2bf(f); l[j] = f2bf(f - bf2f(h[j]));
        }
        size_t o = (size_t)n*KDIM + kc*8;
        *(ushort4*)(woTh + o)     = make_ushort4(h[0],h[1],h[2],h[3]);
        *(ushort4*)(woTh + o + 4) = make_ushort4(h[4],h[5],h[6],h[7]);
        *(ushort4*)(woTl + o)     = make_ushort4(l[0],l[1],l[2],l[3]);
        *(ushort4*)(woTl + o + 4) = make_ushort4(l[4],l[5],l[6],l[7]);
    } else {                                 // bias prep
        const int sub = tid >> 7, st = tid & 127;
        const int lid = (bx-4326)*2 + sub;   // 0..3583 = h(7) x qt(32) x mtp(16)
        const int mtp = lid & 15, qt = (lid>>4) & 31, h = lid >> 9;
#pragma unroll
        for (int it = 0; it < 4; ++it) {
            int idx = it*128 + st;           // 512 float4 = 32 rows x 16 f4
            int row = idx >> 4, c4 = (idx & 15)*4;
            float4 v = *(const float4*)(eb + ((size_t)(h*NSEQ + qt*32 + row))*NSEQ
                                           + mtp*64 + c4);
            T2[sub][row][c4+0]=v.x; T2[sub][row][c4+1]=v.y;
            T2[sub][row][c4+2]=v.z; T2[sub][row][c4+3]=v.w;
        }
        __syncthreads();
        const int half = st >> 6, slane = st & 63;
        const int slq = slane & 31, slh = slane >> 5;
        const int mt = mtp*2 + half;
        unsigned short o[16];
#pragma unroll
        for (int g = 0; g < 4; ++g)
#pragma unroll
            for (int j = 0; j < 4; ++j)
                o[g*4+j] = f2h(T2[sub][slq][half*32 + j + 8*g + 4*slh] * SCALE_F);
        unsigned short* dst = bp + (((size_t)(h*32+qt))*32 + mt)*1024 + slane*16;
        *(ushort4*)(dst+0)  = make_ushort4(o[0],o[1],o[2],o[3]);
        *(ushort4*)(dst+4)  = make_ushort4(o[4],o[5],o[6],o[7]);
        *(ushort4*)(dst+8)  = make_ushort4(o[8],o[9],o[10],o[11]);
        *(ushort4*)(dst+12) = make_ushort4(o[12],o[13],o[14],o[15]);
    }
}

// ---------------------------------------------------------------------------
// gemm1: qv = x @ w_qv, single bf16, register-only, 32x64 tile, depth-2
// prefetch. grid (256, 14), block 64 (1 wave). 3584 waves.
// ---------------------------------------------------------------------------
__global__ __launch_bounds__(64, 4)
void gemm1_r7(const unsigned short* __restrict__ Ah, const unsigned short* __restrict__ Bh,
              unsigned short* __restrict__ qd, unsigned short* __restrict__ vTd)
{
    const int lane = threadIdx.x;
    const int lq = lane & 31, lh = lane >> 5;
    const int m0 = blockIdx.x * 32;
    const int y  = blockIdx.y;
    const int n0 = y * 64;
    const unsigned short* aB = Ah + (size_t)(m0 + lq)*KDIM + lh*8;
    const unsigned short* bB = Bh + (size_t)(n0 + lq)*KDIM + lh*8;

    floatx16 acc[2] = {};
    short8 aR[3][2], bR[3][4];
#define LD1(kt, sl) {                                                          \
    _Pragma("unroll") for (int c = 0; c < 2; ++c) {                            \
        aR[sl][c] = *(const short8*)(aB + (kt)*32 + c*16);                     \
        _Pragma("unroll") for (int fn = 0; fn < 2; ++fn)                       \
            bR[sl][fn*2+c] = *(const short8*)(bB + (size_t)fn*32*KDIM + (kt)*32 + c*16); } }

    LD1(0, 0) LD1(1, 1)
#pragma unroll
    for (int kt = 0; kt < 14; ++kt) {
        if (kt < 12) LD1(kt+2, (kt+2)%3)
        const int sl = kt % 3;
#pragma unroll
        for (int c = 0; c < 2; ++c)
#pragma unroll
            for (int fn = 0; fn < 2; ++fn)
                acc[fn] = MFMA32(aR[sl][c], bR[sl][fn*2+c], acc[fn]);
    }
#undef LD1

#pragma unroll
    for (int fn = 0; fn < 2; ++fn) {
        const int gn = n0 + fn*32 + lq;
        const int hcol = gn >> 6, d = gn & 63;
#pragma unroll
        for (int r = 0; r < 16; ++r) {
            const int gm = m0 + (r&3) + 8*(r>>2) + 4*lh;
            const int b = gm >> 10, ns = gm & 1023;
            unsigned short h = f2bf(acc[fn][r]);
            if (hcol < NHEAD)
                qd[((size_t)((b*NHEAD + hcol)*NSEQ + ns))*HDIM + d] = h;
            else
                vTd[((size_t)((b*NHEAD + hcol - NHEAD)*HDIM + d))*NSEQ + ns] = h;
        }
    }
}

// ---------------------------------------------------------------------------
// attn5: barrier-free, LDS-free flash attention with m-split partials.
// 1 wave = 32 q-rows x half the m-range (512). P transposed D->A-frag via
// shfl_xor(.,32) quad exchange. Depth-2 register prefetch of K/V/bias.
// Writes unnormalized partial O (fp32) + partial l. grid (64,7,8), block 64.
// ---------------------------------------------------------------------------
__global__ __launch_bounds__(64, 2)
void attn5(const unsigned short* __restrict__ qh_g, const unsigned short* __restrict__ vTh,
           const unsigned short* __restrict__ ekh, const unsigned short* __restrict__ bp,
           float* __restrict__ pO, float* __restrict__ pl)
{
    const int lane = threadIdx.x;
    const int lq = lane & 31, lh = lane >> 5;
    const int qt = blockIdx.x & 31, ms = blockIdx.x >> 5;
    const int head = blockIdx.y, b = blockIdx.z;
    const int bh = b*NHEAD + head;
    const int ms16 = ms * 16;

    short8 qf[4];
#pragma unroll
    for (int c = 0; c < 4; ++c)
        qf[c] = *(const short8*)(qh_g +
            ((size_t)(bh*NSEQ) + qt*32 + lq)*HDIM + c*16 + lh*8);

    const unsigned short* kB = ekh + ((size_t)head*NSEQ + lq)*HDIM + lh*8;
    const unsigned short* vB = vTh + ((size_t)(bh*HDIM) + lq)*NSEQ;
    const unsigned short* bB = bp + ((size_t)(head*32 + qt))*32*1024 + lane*16;

    short8 kR[3][4], vR[3][4], bR[3][2];
#define PREF(J, sl) { const int mm = ms16 + (J);                               \
    _Pragma("unroll") for (int c = 0; c < 4; ++c)                              \
        kR[sl][c] = *(const short8*)(kB + (size_t)mm*2048 + c*16);             \
    _Pragma("unroll") for (int fn = 0; fn < 2; ++fn)                           \
    _Pragma("unroll") for (int c2 = 0; c2 < 2; ++c2)                           \
        vR[sl][fn*2+c2] = *(const short8*)(vB + (size_t)(fn*32)*NSEQ + mm*32 + c2*16 + lh*8); \
    bR[sl][0] = *(const short8*)(bB + (size_t)mm*1024);                        \
    bR[sl][1] = *(const short8*)(bB + (size_t)mm*1024 + 8); }

    floatx16 O[2] = {};
    float ls = 0.f;

    PREF(0, 0) PREF(1, 1)
#pragma unroll
    for (int sec = 0; sec < 16; ++sec) {
        if (sec < 14) PREF(sec+2, (sec+2)%3)
        const int sl = sec % 3;

        floatx16 Sa = {}, Sb = {};
        Sa = MFMA32(kR[sl][0], qf[0], Sa);
        Sb = MFMA32(kR[sl][2], qf[2], Sb);
        Sa = MFMA32(kR[sl][1], qf[1], Sa);
        Sb = MFMA32(kR[sl][3], qf[3], Sb);

        u32 Pq[4][2];
#pragma unroll
        for (int g = 0; g < 4; ++g) {
            unsigned short hb[4];
#pragma unroll
            for (int j = 0; j < 4; ++j) {
                const int r = g*4 + j;
                float s = Sa[r] + Sb[r];
                float bs = h2f((unsigned short)bR[sl][g>>1][(g&1)*4 + j]);
                float pv = __expf(fmaf(s, SCALE_F, bs));
                ls += pv;
                hb[j] = f2bf(pv);
            }
            Pq[g][0] = (u32)hb[0] | ((u32)hb[1] << 16);
            Pq[g][1] = (u32)hb[2] | ((u32)hb[3] << 16);
        }
        u32 pp[4][2];
#pragma unroll
        for (int g = 0; g < 4; ++g) {
            pp[g][0] = (u32)__shfl_xor((int)Pq[g][0], 32);
            pp[g][1] = (u32)__shfl_xor((int)Pq[g][1], 32);
        }
#pragma unroll
        for (int c2 = 0; c2 < 2; ++c2) {
            int4v iv;
            iv.x = lh ? (int)pp[2*c2+1][0] : (int)Pq[2*c2][0];
            iv.y = lh ? (int)pp[2*c2+1][1] : (int)Pq[2*c2][1];
            iv.z = lh ? (int)Pq[2*c2+1][0] : (int)pp[2*c2][0];
            iv.w = lh ? (int)Pq[2*c2+1][1] : (int)pp[2*c2][1];
            short8 af = i4_to_s8(iv);
            O[0] = MFMA32(af, vR[sl][0*2+c2], O[0]);
            O[1] = MFMA32(af, vR[sl][1*2+c2], O[1]);
        }
    }
#undef PREF

    float lt = ls + __shfl_xor(ls, 32);
    if (lh == 0) pl[(size_t)(ms*56 + bh)*NSEQ + qt*32 + lq] = lt;

    float* base = pO + ((size_t)(ms*56 + bh)*NSEQ + qt*32)*HDIM;
#pragma unroll
    for (int fn = 0; fn < 2; ++fn)
#pragma unroll
        for (int r = 0; r < 16; ++r) {
            const int qr = (r&3) + 8*(r>>2) + 4*lh;
            base[(size_t)qr*HDIM + fn*32 + lq] = O[fn][r];
        }
}

// ---------------------------------------------------------------------------
// combine: O = (O0+O1)/(l0+l1), split to aoh/aol bf16. grid 3584 x 256.
// ---------------------------------------------------------------------------
__global__ __launch_bounds__(256)
void combine(const float* __restrict__ pO, const float* __restrict__ pl,
             unsigned short* __restrict__ aoh, unsigned short* __restrict__ aol)
{
    const int idx = blockIdx.x*256 + threadIdx.x;   // 917504
    const int row = idx >> 4, d4 = (idx & 15) * 4;
    const float inv = 1.0f / (pl[row] + pl[NROW + row]);
    const float* p0 = pO + (size_t)row*HDIM + d4;
    const float* p1 = p0 + (size_t)NROW*HDIM;
    float4 a = *(const float4*)p0;
    float4 c = *(const float4*)p1;
    float v[4] = {(a.x+c.x)*inv, (a.y+c.y)*inv, (a.z+c.z)*inv, (a.w+c.w)*inv};
    const int bh = row >> 10, q = row & 1023;
    const int bi = bh / 7, head = bh - bi*7;
    const size_t dst = ((size_t)(bi*NSEQ + q))*DIMM + head*HDIM + d4;
    ushort4 h, l;
    h.x = f2bf(v[0]); l.x = f2bf(v[0] - bf2f(h.x));
    h.y = f2bf(v[1]); l.y = f2bf(v[1] - bf2f(h.y));
    h.z = f2bf(v[2]); l.z = f2bf(v[2] - bf2f(h.z));
    h.w = f2bf(v[3]); l.w = f2bf(v[3] - bf2f(h.w));
    *(ushort4*)(aoh + dst) = h;
    *(ushort4*)(aol + dst) = l;
}

// ---------------------------------------------------------------------------
// gemm2: out = ao @ w_out + b_out, 3-term split-2, 32x64 tile, K-split x2
// (2 waves/block, end combine via LDS). grid (256, 7), block 128.
// ---------------------------------------------------------------------------
__global__ __launch_bounds__(128, 3)
void gemm2_r7(const unsigned short* __restrict__ Ah, const unsigned short* __restrict__ Al,
              const unsigned short* __restrict__ Bh, const unsigned short* __restrict__ Bl,
              const float* __restrict__ bias, float* __restrict__ out)
{
    __shared__ float sAcc[2048];
    const int tid = threadIdx.x;
    const int w = tid >> 6, lane = tid & 63;
    const int lq = lane & 31, lh = lane >> 5;
    const int m0 = blockIdx.x * 32, n0 = blockIdx.y * 64;
    const int kb = w * 224;

    const unsigned short* aBh = Ah + (size_t)(m0 + lq)*KDIM + kb + lh*8;
    const unsigned short* aBl = Al + (size_t)(m0 + lq)*KDIM + kb + lh*8;
    const unsigned short* bBh = Bh + (size_t)(n0 + lq)*KDIM + kb + lh*8;
    const unsigned short* bBl = Bl + (size_t)(n0 + lq)*KDIM + kb + lh*8;

    floatx16 acc[2] = {};
    short8 aH[2][2], aL[2][2], bH[2][4], bL[2][4];
#define LD2(kt, sl) {                                                          \
    _Pragma("unroll") for (int c = 0; c < 2; ++c) {                            \
        aH[sl][c] = *(const short8*)(aBh + (kt)*32 + c*16);                    \
        aL[sl][c] = *(const short8*)(aBl + (kt)*32 + c*16);                    \
        _Pragma("unroll") for (int fn = 0; fn < 2; ++fn) {                     \
            bH[sl][fn*2+c] = *(const short8*)(bBh + (size_t)fn*32*KDIM + (kt)*32 + c*16); \
            bL[sl][fn*2+c] = *(const short8*)(bBl + (size_t)fn*32*KDIM + (kt)*32 + c*16); } } }

    LD2(0, 0)
#pragma unroll
    for (int kt = 0; kt < 7; ++kt) {
        if (kt < 6) LD2(kt+1, (kt+1)&1)
        const int sl = kt & 1;
#pragma unroll
        for (int c = 0; c < 2; ++c)
#pragma unroll
            for (int fn = 0; fn < 2; ++fn) {
                acc[fn] = MFMA32(aH[sl][c], bH[sl][fn*2+c], acc[fn]);
                acc[fn] = MFMA32(aL[sl][c], bH[sl][fn*2+c], acc[fn]);
                acc[fn] = MFMA32(aH[sl][c], bL[sl][fn*2+c], acc[fn]);
            }
    }
#undef LD2

    if (w == 1) {
#pragma unroll
        for (int fn = 0; fn < 2; ++fn)
#pragma unroll
            for (int p4 = 0; p4 < 4; ++p4)
                *(float4*)&sAcc[lane*32 + fn*16 + p4*4] =
                    make_float4(acc[fn][p4*4], acc[fn][p4*4+1],
                                acc[fn][p4*4+2], acc[fn][p4*4+3]);
    }
    __syncthreads();
    if (w == 0) {
#pragma unroll
        for (int fn = 0; fn < 2; ++fn) {
            const int gn = n0 + fn*32 + lq;
            const float bv = bias[gn];
#pragma unroll
            for (int r = 0; r < 16; ++r) {
                const int gm = m0 + (r&3) + 8*(r>>2) + 4*lh;
                out[(size_t)gm*DIMM + gn] = acc[fn][r] + sAcc[lane*32 + fn*16 + r] + bv;
            }
        }
    }
}

// ---------------------------------------------------------------------------
extern "C" void kernel_launch(void* const* d_in, const int* in_sizes, int n_in,
                              void* d_out, int out_size, void* d_ws, size_t ws_size,
                              hipStream_t stream)
{
    const float* x    = (const float*)d_in[0];
    const float* wqv  = (const float*)d_in[1];
    const float* ek   = (const float*)d_in[2];
    const float* eb   = (const float*)d_in[3];
    const float* wout = (const float*)d_in[4];
    const float* bout = (const float*)d_in[5];
    float* out = (float*)d_out;

    const size_t MK = (size_t)MROWS*KDIM;        // 3,670,016
    const size_t EK = (size_t)NHEAD*NSEQ*HDIM;   // 458,752
    unsigned short* p = (unsigned short*)d_ws;
    unsigned short* xh    = p;  p += MK;                      // dead after gemm1
    unsigned short* wqvTh = p;  p += (size_t)896*KDIM;
    unsigned short* woTh  = p;  p += (size_t)448*KDIM;
    unsigned short* woTl  = p;  p += (size_t)448*KDIM;
    unsigned short* ekh   = p;  p += EK;
    unsigned short* qh    = p;  p += MK;
    unsigned short* vTh   = p;  p += MK;
    unsigned short* bp    = p;  p += (size_t)NHEAD*NSEQ*NSEQ; // fp16
    unsigned short* aol   = p;  p += MK;
    float* pO = (float*)p;      p += 2*(size_t)NROW*HDIM*2;   // 2 slabs fp32
    float* pl = (float*)p;      p += 2*(size_t)NROW*2;
    unsigned short* aoh = xh;   // alias (xh dead after gemm1)

    prep_all<<<6118, 256, 0, stream>>>(x, ek, wqv, wout, eb,
                                       xh, ekh, wqvTh, woTh, woTl, bp);
    gemm1_r7<<<dim3(256, 14), 64, 0, stream>>>(xh, wqvTh, qh, vTh);
    attn5<<<dim3(64, NHEAD, BATCH), 64, 0, stream>>>(qh, vTh, ekh, bp, pO, pl);
    combine<<<3584, 256, 0, stream>>>(pO, pl, aoh, aol);
    gemm2_r7<<<dim3(256, 7), 128, 0, stream>>>(aoh, aol, woTh, woTl, bout, out);
}